// Round 1
// baseline (281.248 us; speedup 1.0000x reference)
//
#include <hip/hip_runtime.h>

#define BATCH 4096
#define NN 128
#define FF 64
#define NC 129          // possible count values 0..128
#define PADDED_ID (-1)

// table2[c][g] = b2[g] + sum_f relu(c*w1[f] + b1[f]) * w2[g*F + f]
__global__ void build_table_kernel(const float* __restrict__ w1,
                                   const float* __restrict__ b1,
                                   const float* __restrict__ w2,
                                   const float* __restrict__ b2,
                                   float* __restrict__ table) {
    int c = blockIdx.x;        // 0..128
    int g = threadIdx.x;       // 0..63
    float cf = (float)c;
    float acc = b2[g];
    #pragma unroll
    for (int f = 0; f < FF; ++f) {
        float h = cf * w1[f] + b1[f];
        h = h > 0.0f ? h : 0.0f;
        acc += h * w2[g * FF + f];
    }
    table[c * FF + g] = acc;
}

__global__ __launch_bounds__(256)
void encode_kernel(const int* __restrict__ src,
                   const int* __restrict__ dst,
                   const float* __restrict__ table,
                   float* __restrict__ out) {
    __shared__ int s_src[NN];
    __shared__ int s_dst[NN];
    __shared__ int s_cA[256];   // [0..127]: src_in_src ; [128..255]: dst_in_dst
    __shared__ int s_cB[256];   // [0..127]: src_in_dst ; [128..255]: dst_in_src
    __shared__ float s_tab[NC * FF];   // 33 KB

    const int b   = blockIdx.x;
    const int tid = threadIdx.x;

    // ---- stage ids ----
    if (tid < NN) s_src[tid] = src[b * NN + tid];
    else          s_dst[tid - NN] = dst[b * NN + (tid - NN)];

    // ---- stage table (2064 float4) ----
    {
        const float4* tg = (const float4*)table;
        float4* ts = (float4*)s_tab;
        #pragma unroll
        for (int idx = tid; idx < (NC * FF) / 4; idx += 256)
            ts[idx] = tg[idx];
    }
    __syncthreads();

    // ---- counts: wave-uniform split (waves 0,1 -> src rows; waves 2,3 -> dst rows) ----
    {
        const int i = tid & (NN - 1);
        const int* A  = (tid < NN) ? s_src : s_dst;
        const int* Bp = (tid < NN) ? s_dst : s_src;
        const int my = A[i];
        int ca = 0, cb = 0;
        #pragma unroll 8
        for (int j = 0; j < NN; ++j) {
            ca += (my == A[j]);
            cb += (my == Bp[j]);
        }
        if (my == PADDED_ID) { ca = 0; cb = 0; }
        s_cA[tid] = ca;
        s_cB[tid] = cb;
    }
    __syncthreads();

    // ---- emit: out_row = table[c0] + table[c1], coalesced float4 stores ----
    const int g4 = tid & 15;        // float4 lane within a 64-feature row
    const int n0 = tid >> 4;        // 0..15
    const float4* tab4 = (const float4*)s_tab;
    float4* out_src = (float4*)out + (size_t)b * NN * (FF / 4);
    float4* out_dst = (float4*)out + (size_t)BATCH * NN * (FF / 4) + (size_t)b * NN * (FF / 4);

    #pragma unroll
    for (int n = n0; n < NN; n += 16) {
        // src output row n
        {
            const int c0 = s_cA[n], c1 = s_cB[n];
            float4 v0 = tab4[c0 * (FF / 4) + g4];
            float4 v1 = tab4[c1 * (FF / 4) + g4];
            float4 r;
            r.x = v0.x + v1.x; r.y = v0.y + v1.y;
            r.z = v0.z + v1.z; r.w = v0.w + v1.w;
            out_src[n * (FF / 4) + g4] = r;
        }
        // dst output row n
        {
            const int c0 = s_cA[n + NN], c1 = s_cB[n + NN];
            float4 v0 = tab4[c0 * (FF / 4) + g4];
            float4 v1 = tab4[c1 * (FF / 4) + g4];
            float4 r;
            r.x = v0.x + v1.x; r.y = v0.y + v1.y;
            r.z = v0.z + v1.z; r.w = v0.w + v1.w;
            out_dst[n * (FF / 4) + g4] = r;
        }
    }
}

extern "C" void kernel_launch(void* const* d_in, const int* in_sizes, int n_in,
                              void* d_out, int out_size, void* d_ws, size_t ws_size,
                              hipStream_t stream) {
    const int*   src = (const int*)d_in[0];
    const int*   dst = (const int*)d_in[1];
    const float* w1  = (const float*)d_in[2];
    const float* b1  = (const float*)d_in[3];
    const float* w2  = (const float*)d_in[4];
    const float* b2  = (const float*)d_in[5];
    float* out   = (float*)d_out;
    float* table = (float*)d_ws;   // 129*64*4 = 33,024 bytes

    build_table_kernel<<<NC, FF, 0, stream>>>(w1, b1, w2, b2, table);
    encode_kernel<<<BATCH, 256, 0, stream>>>(src, dst, table, out);
}

// Round 2
// 277.811 us; speedup vs baseline: 1.0124x; 1.0124x over previous
//
#include <hip/hip_runtime.h>

#define BATCH 4096
#define NN 128
#define FF 64
#define NC 129          // possible count values 0..128
#define PADDED_ID (-1)
#define BPB 4           // batches per block
#define GRID (BATCH / BPB)   // 1024 blocks = 4 blocks/CU exactly

// table[c][g] = b2[g] + sum_f relu(c*w1[f] + b1[f]) * w2[g*F + f]
__global__ void build_table_kernel(const float* __restrict__ w1,
                                   const float* __restrict__ b1,
                                   const float* __restrict__ w2,
                                   const float* __restrict__ b2,
                                   float* __restrict__ table) {
    int c = blockIdx.x;        // 0..128
    int g = threadIdx.x;       // 0..63
    float cf = (float)c;
    float acc = b2[g];
    #pragma unroll
    for (int f = 0; f < FF; ++f) {
        float h = cf * w1[f] + b1[f];
        h = h > 0.0f ? h : 0.0f;
        acc += h * w2[g * FF + f];
    }
    table[c * FF + g] = acc;
}

__global__ __launch_bounds__(256)
void encode_kernel(const int* __restrict__ src,
                   const int* __restrict__ dst,
                   const float* __restrict__ table,
                   float* __restrict__ out) {
    __shared__ float s_tab[NC * FF];   // 33 KB
    __shared__ int   s_ids[2 * NN];    // [0..127]=src, [128..255]=dst
    __shared__ int   s_cA[2 * NN];     // self-counts (src_in_src / dst_in_dst)
    __shared__ int   s_cB[2 * NN];     // cross-counts (src_in_dst / dst_in_src)

    const int tid = threadIdx.x;

    // ---- stage table ONCE per block (amortized over BPB batches) ----
    {
        const float4* tg = (const float4*)table;
        float4* ts = (float4*)s_tab;
        #pragma unroll
        for (int idx = tid; idx < (NC * FF) / 4; idx += 256)
            ts[idx] = tg[idx];
    }

    const int g4 = tid & 15;        // float4 lane within a 64-feature row
    const int n0 = tid >> 4;        // 0..15
    const float4* tab4 = (const float4*)s_tab;

    for (int k = 0; k < BPB; ++k) {
        const int b = blockIdx.x * BPB + k;

        __syncthreads();   // emit of prev iter done before s_ids/s_cA reuse
        if (tid < NN) s_ids[tid]      = src[b * NN + tid];
        else          s_ids[tid]      = dst[b * NN + (tid - NN)];
        __syncthreads();   // (k==0: also covers table staging)

        // ---- counts: waves 0,1 -> src rows; waves 2,3 -> dst rows ----
        {
            const int i  = tid & (NN - 1);
            const int*  A  = (tid < NN) ? s_ids : s_ids + NN;
            const int*  Bp = (tid < NN) ? s_ids + NN : s_ids;
            const int my = A[i];
            const int4* A4 = (const int4*)A;
            const int4* B4 = (const int4*)Bp;
            int ca = 0, cb = 0;
            #pragma unroll
            for (int j = 0; j < NN / 4; ++j) {
                int4 a = A4[j];
                int4 bb = B4[j];
                ca += (my == a.x) + (my == a.y) + (my == a.z) + (my == a.w);
                cb += (my == bb.x) + (my == bb.y) + (my == bb.z) + (my == bb.w);
            }
            if (my == PADDED_ID) { ca = 0; cb = 0; }
            s_cA[tid] = ca;
            s_cB[tid] = cb;
        }
        __syncthreads();

        // ---- emit: out_row = table[c0] + table[c1], 1 KB-contiguous wave stores ----
        float4* out_src = (float4*)out + (size_t)b * (NN * FF / 4);
        float4* out_dst = (float4*)out + (size_t)BATCH * (NN * FF / 4)
                                       + (size_t)b * (NN * FF / 4);
        #pragma unroll
        for (int n = n0; n < NN; n += 16) {
            {
                const int c0 = s_cA[n], c1 = s_cB[n];
                float4 v0 = tab4[c0 * (FF / 4) + g4];
                float4 v1 = tab4[c1 * (FF / 4) + g4];
                float4 r;
                r.x = v0.x + v1.x; r.y = v0.y + v1.y;
                r.z = v0.z + v1.z; r.w = v0.w + v1.w;
                out_src[n * (FF / 4) + g4] = r;
            }
            {
                const int c0 = s_cA[NN + n], c1 = s_cB[NN + n];
                float4 v0 = tab4[c0 * (FF / 4) + g4];
                float4 v1 = tab4[c1 * (FF / 4) + g4];
                float4 r;
                r.x = v0.x + v1.x; r.y = v0.y + v1.y;
                r.z = v0.z + v1.z; r.w = v0.w + v1.w;
                out_dst[n * (FF / 4) + g4] = r;
            }
        }
    }
}

extern "C" void kernel_launch(void* const* d_in, const int* in_sizes, int n_in,
                              void* d_out, int out_size, void* d_ws, size_t ws_size,
                              hipStream_t stream) {
    const int*   src = (const int*)d_in[0];
    const int*   dst = (const int*)d_in[1];
    const float* w1  = (const float*)d_in[2];
    const float* b1  = (const float*)d_in[3];
    const float* w2  = (const float*)d_in[4];
    const float* b2  = (const float*)d_in[5];
    float* out   = (float*)d_out;
    float* table = (float*)d_ws;   // 129*64*4 = 33,024 bytes

    build_table_kernel<<<NC, FF, 0, stream>>>(w1, b1, w2, b2, table);
    encode_kernel<<<GRID, 256, 0, stream>>>(src, dst, table, out);
}

// Round 3
// 275.353 us; speedup vs baseline: 1.0214x; 1.0089x over previous
//
#include <hip/hip_runtime.h>

#define BATCH 4096
#define NN 128
#define FF 64
#define NC 129          // possible count values 0..128
#define HIST 1000       // ids are randint(0, 1000)
#define PADDED_ID (-1)
#define BPB 4           // batches per block
#define GRID (BATCH / BPB)   // 1024 blocks = 4 blocks/CU exactly

// table[c][g] = b2[g] + sum_f relu(c*w1[f] + b1[f]) * w2[g*F + f]
__global__ void build_table_kernel(const float* __restrict__ w1,
                                   const float* __restrict__ b1,
                                   const float* __restrict__ w2,
                                   const float* __restrict__ b2,
                                   float* __restrict__ table) {
    int c = blockIdx.x;        // 0..128
    int g = threadIdx.x;       // 0..63
    float cf = (float)c;
    float acc = b2[g];
    #pragma unroll
    for (int f = 0; f < FF; ++f) {
        float h = cf * w1[f] + b1[f];
        h = h > 0.0f ? h : 0.0f;
        acc += h * w2[g * FF + f];
    }
    table[c * FF + g] = acc;
}

__global__ __launch_bounds__(256)
void encode_kernel(const int* __restrict__ src,
                   const int* __restrict__ dst,
                   const float* __restrict__ table,
                   float* __restrict__ out) {
    __shared__ float    s_tab[NC * FF];   // 33,024 B
    __shared__ unsigned s_hist[HIST];     //  4,000 B: low16 = count in src, high16 = count in dst
    __shared__ unsigned s_cnt[2 * NN];    //  1,024 B: packed (c_self-ish | c_other<<16), order irrelevant (sum is symmetric)

    const int tid = threadIdx.x;

    // ---- stage table ONCE per block ----
    {
        const float4* tg = (const float4*)table;
        float4* ts = (float4*)s_tab;
        #pragma unroll
        for (int idx = tid; idx < (NC * FF) / 4; idx += 256)
            ts[idx] = tg[idx];
    }

    const int g4 = tid & 15;        // float4 lane within a 64-feature row
    const int n0 = tid >> 4;        // 0..15
    const float4* tab4 = (const float4*)s_tab;

    for (int k = 0; k < BPB; ++k) {
        const int b = blockIdx.x * BPB + k;

        // my id: threads 0..127 own src rows, 128..255 own dst rows
        const int my = (tid < NN) ? src[b * NN + tid] : dst[b * NN + (tid - NN)];
        const unsigned inc = (tid < NN) ? 1u : 0x10000u;

        __syncthreads();   // prev-iter emit (reads s_cnt/s_tab) done; also covers k==0 staging
        #pragma unroll
        for (int i = tid; i < HIST; i += 256) s_hist[i] = 0u;
        __syncthreads();

        if (my != PADDED_ID && (unsigned)my < HIST)
            atomicAdd(&s_hist[my], inc);
        __syncthreads();

        {
            // For a src row: low = src_in_src, high = src_in_dst.
            // For a dst row: low = dst_in_src, high = dst_in_dst.
            // Emit computes table[lo]+table[hi] -- symmetric, order irrelevant.
            unsigned h = (my != PADDED_ID && (unsigned)my < HIST) ? s_hist[my] : 0u;
            s_cnt[tid] = h;
        }
        __syncthreads();

        // ---- emit: out_row = table[c0] + table[c1], 1 KB-contiguous wave stores ----
        float4* out_src = (float4*)out + (size_t)b * (NN * FF / 4);
        float4* out_dst = out_src + (size_t)BATCH * (NN * FF / 4);
        #pragma unroll
        for (int n = n0; n < NN; n += 16) {
            {
                const unsigned h = s_cnt[n];
                const int c0 = (int)(h & 0xffffu), c1 = (int)(h >> 16);
                float4 v0 = tab4[c0 * (FF / 4) + g4];
                float4 v1 = tab4[c1 * (FF / 4) + g4];
                float4 r;
                r.x = v0.x + v1.x; r.y = v0.y + v1.y;
                r.z = v0.z + v1.z; r.w = v0.w + v1.w;
                out_src[n * (FF / 4) + g4] = r;
            }
            {
                const unsigned h = s_cnt[NN + n];
                const int c0 = (int)(h & 0xffffu), c1 = (int)(h >> 16);
                float4 v0 = tab4[c0 * (FF / 4) + g4];
                float4 v1 = tab4[c1 * (FF / 4) + g4];
                float4 r;
                r.x = v0.x + v1.x; r.y = v0.y + v1.y;
                r.z = v0.z + v1.z; r.w = v0.w + v1.w;
                out_dst[n * (FF / 4) + g4] = r;
            }
        }
    }
}

extern "C" void kernel_launch(void* const* d_in, const int* in_sizes, int n_in,
                              void* d_out, int out_size, void* d_ws, size_t ws_size,
                              hipStream_t stream) {
    const int*   src = (const int*)d_in[0];
    const int*   dst = (const int*)d_in[1];
    const float* w1  = (const float*)d_in[2];
    const float* b1  = (const float*)d_in[3];
    const float* w2  = (const float*)d_in[4];
    const float* b2  = (const float*)d_in[5];
    float* out   = (float*)d_out;
    float* table = (float*)d_ws;   // 129*64*4 = 33,024 bytes

    build_table_kernel<<<NC, FF, 0, stream>>>(w1, b1, w2, b2, table);
    encode_kernel<<<GRID, 256, 0, stream>>>(src, dst, table, out);
}

// Round 4
// 275.110 us; speedup vs baseline: 1.0223x; 1.0009x over previous
//
#include <hip/hip_runtime.h>

#define BATCH 4096
#define NN 128
#define FF 64
#define NC 129          // possible count values 0..128
#define HIST 1000       // ids are randint(0, 1000)
#define PADDED_ID (-1)

// table[c][g] = b2[g] + sum_f relu(c*w1[f] + b1[f]) * w2[g*F + f]
__global__ void build_table_kernel(const float* __restrict__ w1,
                                   const float* __restrict__ b1,
                                   const float* __restrict__ w2,
                                   const float* __restrict__ b2,
                                   float* __restrict__ table) {
    int c = blockIdx.x;        // 0..128
    int g = threadIdx.x;       // 0..63
    float cf = (float)c;
    float acc = b2[g];
    #pragma unroll
    for (int f = 0; f < FF; ++f) {
        float h = cf * w1[f] + b1[f];
        h = h > 0.0f ? h : 0.0f;
        acc += h * w2[g * FF + f];
    }
    table[c * FF + g] = acc;
}

// One block per batch. LDS = 5 KB -> 8 blocks/CU (32 waves, wave cap).
// Table (33 KB) is read from global in the emit loop: L1-resident, coalesced.
__global__ __launch_bounds__(256, 8)
void encode_kernel(const int* __restrict__ src,
                   const int* __restrict__ dst,
                   const float* __restrict__ table,
                   float* __restrict__ out) {
    __shared__ unsigned s_hist[HIST];   // low16 = count in src, high16 = count in dst
    __shared__ unsigned s_cnt[2 * NN];  // per-row packed (cnt_in_src | cnt_in_dst<<16)

    const int b   = blockIdx.x;
    const int tid = threadIdx.x;

    // threads 0..127 own src rows, 128..255 own dst rows (coalesced id loads)
    const int my = (tid < NN) ? src[b * NN + tid] : dst[b * NN + (tid - NN)];
    const unsigned inc = (tid < NN) ? 1u : 0x10000u;
    const bool valid = (my != PADDED_ID) && ((unsigned)my < HIST);

    #pragma unroll
    for (int i = tid; i < HIST; i += 256) s_hist[i] = 0u;
    __syncthreads();

    if (valid) atomicAdd(&s_hist[my], inc);
    __syncthreads();

    // src row: low=src_in_src, high=src_in_dst; dst row: low=dst_in_src, high=dst_in_dst.
    // Emit computes table[lo]+table[hi] -- symmetric in (lo,hi).
    s_cnt[tid] = valid ? s_hist[my] : 0u;
    __syncthreads();

    // ---- emit: out_row = table[c0] + table[c1]; each wave stores 1 KB contiguous ----
    const int g4 = tid & 15;        // float4 lane within a 64-float row
    const int n0 = tid >> 4;        // 0..15
    const float4* __restrict__ tab4 = (const float4*)table;
    float4* out_src = (float4*)out + (size_t)b * (NN * FF / 4);
    float4* out_dst = out_src + (size_t)BATCH * (NN * FF / 4);

    #pragma unroll
    for (int n = n0; n < NN; n += 16) {
        {
            const unsigned h = s_cnt[n];
            float4 v0 = tab4[(h & 0xffffu) * (FF / 4) + g4];
            float4 v1 = tab4[(h >> 16)     * (FF / 4) + g4];
            float4 r;
            r.x = v0.x + v1.x; r.y = v0.y + v1.y;
            r.z = v0.z + v1.z; r.w = v0.w + v1.w;
            out_src[n * (FF / 4) + g4] = r;
        }
        {
            const unsigned h = s_cnt[NN + n];
            float4 v0 = tab4[(h & 0xffffu) * (FF / 4) + g4];
            float4 v1 = tab4[(h >> 16)     * (FF / 4) + g4];
            float4 r;
            r.x = v0.x + v1.x; r.y = v0.y + v1.y;
            r.z = v0.z + v1.z; r.w = v0.w + v1.w;
            out_dst[n * (FF / 4) + g4] = r;
        }
    }
}

extern "C" void kernel_launch(void* const* d_in, const int* in_sizes, int n_in,
                              void* d_out, int out_size, void* d_ws, size_t ws_size,
                              hipStream_t stream) {
    const int*   src = (const int*)d_in[0];
    const int*   dst = (const int*)d_in[1];
    const float* w1  = (const float*)d_in[2];
    const float* b1  = (const float*)d_in[3];
    const float* w2  = (const float*)d_in[4];
    const float* b2  = (const float*)d_in[5];
    float* out   = (float*)d_out;
    float* table = (float*)d_ws;   // 129*64*4 = 33,024 bytes

    build_table_kernel<<<NC, FF, 0, stream>>>(w1, b1, w2, b2, table);
    encode_kernel<<<BATCH, 256, 0, stream>>>(src, dst, table, out);
}